// Round 1
// baseline (619.326 us; speedup 1.0000x reference)
//
#include <hip/hip_runtime.h>

// Anchor3DHead fused 1x1-conv heads: x[B,C,H,W] fp32, three weight sets.
// cls: C->18, reg: C->42, dir: C->12. Output = concat(cls, reg, dir) flat,
// each [B, O, H, W] channels-first fp32.

constexpr int Bn   = 4;
constexpr int Cc   = 384;
constexpr int Hh   = 248;
constexpr int Ww   = 216;
constexpr int HW   = Hh * Ww;          // 53568  (= 64 * 837)
constexpr int NPIX = Bn * HW;          // 214272 (= 256 * 837)
constexpr int NCLS = 18;
constexpr int NREG = 42;
constexpr int NDIR = 12;

typedef float v2f __attribute__((ext_vector_type(2)));

__global__ __launch_bounds__(256) void head_fused(
    const float* __restrict__ x,
    const float* __restrict__ wc, const float* __restrict__ bc,
    const float* __restrict__ wr, const float* __restrict__ br,
    const float* __restrict__ wd, const float* __restrict__ bd,
    float* __restrict__ out)
{
    const int g = blockIdx.x * 256 + threadIdx.x;   // < 214272 exactly
    const int b = g / HW;
    const int p = g - b * HW;

    const float* __restrict__ xb = x + (size_t)b * Cc * HW + p;

    v2f ac[NCLS / 2];
    v2f ar[NREG / 2];
    v2f ad[NDIR / 2];
    #pragma unroll
    for (int o = 0; o < NCLS / 2; ++o) { ac[o][0] = bc[2*o]; ac[o][1] = bc[2*o+1]; }
    #pragma unroll
    for (int o = 0; o < NREG / 2; ++o) { ar[o][0] = br[2*o]; ar[o][1] = br[2*o+1]; }
    #pragma unroll
    for (int o = 0; o < NDIR / 2; ++o) { ad[o][0] = bd[2*o]; ad[o][1] = bd[2*o+1]; }

    for (int c = 0; c < Cc; ++c) {
        const float xs = xb[(size_t)c * HW];
        v2f xv; xv[0] = xs; xv[1] = xs;

        const v2f* __restrict__ wcc = (const v2f*)(wc + c * NCLS);
        #pragma unroll
        for (int o = 0; o < NCLS / 2; ++o)
            ac[o] = __builtin_elementwise_fma(xv, wcc[o], ac[o]);

        const v2f* __restrict__ wrc = (const v2f*)(wr + c * NREG);
        #pragma unroll
        for (int o = 0; o < NREG / 2; ++o)
            ar[o] = __builtin_elementwise_fma(xv, wrc[o], ar[o]);

        const v2f* __restrict__ wdc = (const v2f*)(wd + c * NDIR);
        #pragma unroll
        for (int o = 0; o < NDIR / 2; ++o)
            ad[o] = __builtin_elementwise_fma(xv, wdc[o], ad[o]);
    }

    // cls region: offset 0, [B, 18, H, W]
    float* __restrict__ oc = out + (size_t)b * NCLS * HW + p;
    #pragma unroll
    for (int o = 0; o < NCLS / 2; ++o) {
        oc[(size_t)(2*o)   * HW] = ac[o][0];
        oc[(size_t)(2*o+1) * HW] = ac[o][1];
    }
    // reg region: offset B*18*HW, [B, 42, H, W]
    float* __restrict__ og = out + (size_t)Bn * NCLS * HW + (size_t)b * NREG * HW + p;
    #pragma unroll
    for (int o = 0; o < NREG / 2; ++o) {
        og[(size_t)(2*o)   * HW] = ar[o][0];
        og[(size_t)(2*o+1) * HW] = ar[o][1];
    }
    // dir region: offset B*(18+42)*HW, [B, 12, H, W]
    float* __restrict__ od = out + (size_t)Bn * (NCLS + NREG) * HW + (size_t)b * NDIR * HW + p;
    #pragma unroll
    for (int o = 0; o < NDIR / 2; ++o) {
        od[(size_t)(2*o)   * HW] = ad[o][0];
        od[(size_t)(2*o+1) * HW] = ad[o][1];
    }
}

extern "C" void kernel_launch(void* const* d_in, const int* in_sizes, int n_in,
                              void* d_out, int out_size, void* d_ws, size_t ws_size,
                              hipStream_t stream) {
    const float* x  = (const float*)d_in[0];
    const float* wc = (const float*)d_in[1];
    const float* bc = (const float*)d_in[2];
    const float* wr = (const float*)d_in[3];
    const float* br = (const float*)d_in[4];
    const float* wd = (const float*)d_in[5];
    const float* bd = (const float*)d_in[6];
    float* out = (float*)d_out;

    dim3 grid(NPIX / 256);   // 837 blocks, exact cover
    dim3 block(256);
    head_fused<<<grid, block, 0, stream>>>(x, wc, bc, wr, br, wd, bd, out);
}

// Round 2
// 531.518 us; speedup vs baseline: 1.1652x; 1.1652x over previous
//
#include <hip/hip_runtime.h>

// Anchor3DHead fused 1x1-conv heads, R2: M-split across waves.
// Block = 256 threads = 4 waves; each block covers 64 pixels (lane = pixel).
// Wave w owns 18 of the 72 output channels over ALL 384 input channels:
//   w0: cls[0..18)   w1: reg[0..18)   w2: reg[18..36)   w3: reg[36..42)+dir[0..12)
// No combine needed; 18 accumulators/thread keeps VGPRs low (8 waves/SIMD),
// grid = 3348 blocks supplies 13 waves/SIMD of demand.

constexpr int Bn   = 4;
constexpr int Cc   = 384;
constexpr int Hh   = 248;
constexpr int Ww   = 216;
constexpr int HW   = Hh * Ww;          // 53568
constexpr int NPIX = Bn * HW;          // 214272 = 64 * 3348
constexpr int NCLS = 18;
constexpr int NREG = 42;
constexpr int NDIR = 12;

// One wave's work: NA outputs from weight matrix wA (row stride LDA), plus
// optionally NB outputs from wB (stride LDB). Weight indices are wave-uniform
// -> scalar loads. x load is one coalesced dword per lane per channel.
template<int NA, int LDA, int NB, int LDB>
__device__ __forceinline__ void cohort_run(
    const float* __restrict__ xb,
    const float* __restrict__ wA, const float* __restrict__ bA,
    float* __restrict__ oA,
    const float* __restrict__ wB, const float* __restrict__ bB,
    float* __restrict__ oB)
{
    float acc[NA + NB];
    #pragma unroll
    for (int j = 0; j < NA; ++j) acc[j] = bA[j];
    #pragma unroll
    for (int j = 0; j < NB; ++j) acc[NA + j] = bB[j];

    #pragma unroll 4
    for (int c = 0; c < Cc; ++c) {
        const float xv = xb[(size_t)c * HW];
        #pragma unroll
        for (int j = 0; j < NA; ++j)
            acc[j] = fmaf(xv, wA[c * LDA + j], acc[j]);
        #pragma unroll
        for (int j = 0; j < NB; ++j)
            acc[NA + j] = fmaf(xv, wB[c * LDB + j], acc[NA + j]);
    }

    #pragma unroll
    for (int j = 0; j < NA; ++j) oA[(size_t)j * HW] = acc[j];
    #pragma unroll
    for (int j = 0; j < NB; ++j) oB[(size_t)j * HW] = acc[NA + j];
}

__global__ __launch_bounds__(256) void head_fused_msplit(
    const float* __restrict__ x,
    const float* __restrict__ wc, const float* __restrict__ bc,
    const float* __restrict__ wr, const float* __restrict__ br,
    const float* __restrict__ wd, const float* __restrict__ bd,
    float* __restrict__ out)
{
    const int w    = threadIdx.x >> 6;       // wave id 0..3 (uniform per wave)
    const int lane = threadIdx.x & 63;
    const int pix  = blockIdx.x * 64 + lane; // < 214272 exactly
    const int b    = pix / HW;
    const int p    = pix - b * HW;

    const float* __restrict__ xb = x + (size_t)b * Cc * HW + p;

    float* __restrict__ outc = out + (size_t)b * NCLS * HW + p;
    float* __restrict__ outr = out + (size_t)Bn * NCLS * HW
                                   + (size_t)b * NREG * HW + p;
    float* __restrict__ outd = out + (size_t)Bn * (NCLS + NREG) * HW
                                   + (size_t)b * NDIR * HW + p;

    if (w == 0) {
        cohort_run<18, NCLS, 0, 1>(xb, wc, bc, outc, wc, bc, outc);
    } else if (w == 1) {
        cohort_run<18, NREG, 0, 1>(xb, wr, br, outr, wr, br, outr);
    } else if (w == 2) {
        cohort_run<18, NREG, 0, 1>(xb, wr + 18, br + 18, outr + (size_t)18 * HW,
                                   wr, br, outr);
    } else {
        cohort_run<6, NREG, 12, NDIR>(xb, wr + 36, br + 36, outr + (size_t)36 * HW,
                                      wd, bd, outd);
    }
}

extern "C" void kernel_launch(void* const* d_in, const int* in_sizes, int n_in,
                              void* d_out, int out_size, void* d_ws, size_t ws_size,
                              hipStream_t stream) {
    const float* x  = (const float*)d_in[0];
    const float* wc = (const float*)d_in[1];
    const float* bc = (const float*)d_in[2];
    const float* wr = (const float*)d_in[3];
    const float* br = (const float*)d_in[4];
    const float* wd = (const float*)d_in[5];
    const float* bd = (const float*)d_in[6];
    float* out = (float*)d_out;

    dim3 grid(NPIX / 64);    // 3348 blocks, exact cover (64 pixels per block)
    dim3 block(256);
    head_fused_msplit<<<grid, block, 0, stream>>>(x, wc, bc, wr, br, wd, bd, out);
}